// Round 9
// baseline (513.344 us; speedup 1.0000x reference)
//
#include <hip/hip_runtime.h>
#include <hip/hip_bf16.h>

#define NN 50000
#define EE 800000
#define NT32 25000                  // 32-edge tiles per graph
#define BPG 1024                    // blocks per graph

typedef __attribute__((ext_vector_type(8))) short bf16x8;
typedef __attribute__((ext_vector_type(4))) float f32x4;
typedef __attribute__((ext_vector_type(4))) unsigned u32x4;

// order-preserving float->u32 encoding for atomicMax scatter-max
__device__ __forceinline__ unsigned enc(float f) {
    unsigned u = __float_as_uint(f);
    return u ^ (unsigned)(((int)u >> 31) | 0x80000000);
}
__device__ __forceinline__ float dec(unsigned u) {
    unsigned v = (u & 0x80000000u) ? (u & 0x7FFFFFFFu) : ~u;
    return __uint_as_float(v);
}
__device__ __forceinline__ unsigned short f2bf(float f) {   // RNE (cold path)
    unsigned u = __float_as_uint(f);
    u += 0x7fffu + ((u >> 16) & 1u);
    return (unsigned short)(u >> 16);
}
__device__ __forceinline__ unsigned pk2(float a, float b) { // v_cvt_pk_bf16_f32
    __hip_bfloat162 t = __float22bfloat162_rn(make_float2(a, b));
    unsigned r;
    __builtin_memcpy(&r, &t, 4);
    return r;
}

__global__ void decode_acc(unsigned* __restrict__ acc, int n) {
    int i = blockIdx.x * blockDim.x + threadIdx.x;
    if (i < n) {
        unsigned u = acc[i];
        ((float*)acc)[i] = (u == 0u) ? 0.0f : dec(u);   // empty -> 0.0 (ref)
    }
}

// 128 threads = 2 waves (w_h = hid/out half). 32-edge tiles. 2 raw barriers
// per tile; register prefetch of next tile's gather; small blocks so 6-9
// blocks/CU dovetail gather/MFMA/atomic phases across the CU.
__global__ __launch_bounds__(128, 3)
void edge_mlp(const float* __restrict__ x1, const float* __restrict__ x2,
              const int* __restrict__ ei1, const int* __restrict__ ei2,
              const float* __restrict__ W1, const float* __restrict__ b1,
              const float* __restrict__ W2, const float* __restrict__ b2,
              unsigned* __restrict__ acc)
{
    __shared__ short e_lds[32 * 128];   // 8 KB, (e&15) XOR-swizzled
    __shared__ short h_lds[32 * 128];   // 8 KB, same swizzle
    __shared__ int srow[2][32];         // double-buffered

    const int tid  = threadIdx.x;
    const int lane = tid & 63;
    const int l15  = lane & 15;
    const int lg   = lane >> 4;
    const int w_h  = tid >> 6;          // wave id: hid/out half

    const int g     = (blockIdx.x >= BPG) ? 1 : 0;
    const int bslot = blockIdx.x & (BPG - 1);
    const int* __restrict__ ei = g ? ei2 : ei1;
    const float* __restrict__ xc = g ? x2 : x1;
    const int goff = g * 64;

    // ---- persistent register weights ----
    bf16x8 a1[4][4];                    // W1^T A-frags [m: hid][s: kstep]
    #pragma unroll
    for (int m = 0; m < 4; ++m)
        #pragma unroll
        for (int s = 0; s < 4; ++s) {
            const float* p = W1 + (size_t)(32 * s + 8 * lg) * 128
                               + (w_h * 64 + 16 * m + l15);
            bf16x8 r;
            #pragma unroll
            for (int i = 0; i < 8; ++i) r[i] = (short)f2bf(p[i * 128]);
            a1[m][s] = r;
        }
    bf16x8 b2f[4][2];                   // W2 B-frags [s: kstep][n: out]
    #pragma unroll
    for (int s = 0; s < 4; ++s)
        #pragma unroll
        for (int n = 0; n < 2; ++n) {
            const float* p = W2 + (size_t)(32 * s + 8 * lg) * 64
                               + (w_h * 32 + 16 * n + l15);
            bf16x8 r;
            #pragma unroll
            for (int i = 0; i < 8; ++i) r[i] = (short)f2bf(p[i * 64]);
            b2f[s][n] = r;
        }
    float4 b1v[4];
    #pragma unroll
    for (int m = 0; m < 4; ++m)
        b1v[m] = *(const float4*)(b1 + w_h * 64 + 16 * m + 4 * lg);
    float b2v[2];
    #pragma unroll
    for (int n = 0; n < 2; ++n) b2v[n] = b2[w_h * 32 + 16 * n + l15];

    // per-lane atomic column base (outc fixed per lane/n)
    unsigned* abase[2];
    #pragma unroll
    for (int n = 0; n < 2; ++n)
        abase[n] = acc + goff + w_h * 32 + 16 * n + l15;

    // ---- gather mapping: thread owns edge ge, float cols 16*gq..+15 ----
    const int ge = tid & 31;
    const int gq = tid >> 5;            // column quarter 0..3
    const int swz = (ge & 15) << 3;     // XOR swizzle, in shorts

    // ---- prologue: idx(t0), idx(t1), issue gather(t0) ----
    int rcur, ccur, rnext, cnext;
    {
        int ta = bslot;
        rcur = ei[ta * 32 + ge];
        ccur = ei[EE + ta * 32 + ge];
        int tb = ta + BPG; if (tb >= NT32) tb = NT32 - 1;
        rnext = ei[tb * 32 + ge];
        cnext = ei[EE + tb * 32 + ge];
    }
    float4 gp0, gp1, gp2, gp3, gq0, gq1, gq2, gq3;
    {
        const float4* pp = (const float4*)(x1 + (size_t)rcur * 64 + 16 * gq);
        const float4* pq = (const float4*)(xc + (size_t)ccur * 64 + 16 * gq);
        gp0 = pp[0]; gp1 = pp[1]; gp2 = pp[2]; gp3 = pp[3];
        gq0 = pq[0]; gq1 = pq[1]; gq2 = pq[2]; gq3 = pq[3];
    }

    int i = 0;
    for (int t = bslot; t < NT32; t += BPG, ++i) {
        const int ib = i & 1;
        // ---- A: write e tile (t) from prefetched regs; srow ----
        if (tid < 32) srow[ib][tid] = rcur;
        {
            short* erow = &e_lds[ge * 128];
            u32x4 v;
            v[0] = pk2(gp0.x, gp0.y); v[1] = pk2(gp0.z, gp0.w);
            v[2] = pk2(gp1.x, gp1.y); v[3] = pk2(gp1.z, gp1.w);
            *(u32x4*)&erow[(16 * gq) ^ swz] = v;
            v[0] = pk2(gp2.x, gp2.y); v[1] = pk2(gp2.z, gp2.w);
            v[2] = pk2(gp3.x, gp3.y); v[3] = pk2(gp3.z, gp3.w);
            *(u32x4*)&erow[(16 * gq + 8) ^ swz] = v;
            v[0] = pk2(gq0.x - gp0.x, gq0.y - gp0.y);
            v[1] = pk2(gq0.z - gp0.z, gq0.w - gp0.w);
            v[2] = pk2(gq1.x - gp1.x, gq1.y - gp1.y);
            v[3] = pk2(gq1.z - gp1.z, gq1.w - gp1.w);
            *(u32x4*)&erow[(64 + 16 * gq) ^ swz] = v;
            v[0] = pk2(gq2.x - gp2.x, gq2.y - gp2.y);
            v[1] = pk2(gq2.z - gp2.z, gq2.w - gp2.w);
            v[2] = pk2(gq3.x - gp3.x, gq3.y - gp3.y);
            v[3] = pk2(gq3.z - gp3.z, gq3.w - gp3.w);
            *(u32x4*)&erow[(64 + 16 * gq + 8) ^ swz] = v;
        }

        // ---- B: rotate idx; prefetch idx(t+2); issue gather(t+1) ----
        rcur = rnext; ccur = cnext;
        {
            int t2 = t + 2 * BPG; if (t2 >= NT32) t2 = NT32 - 1;
            rnext = ei[t2 * 32 + ge];
            cnext = ei[EE + t2 * 32 + ge];
        }
        if (t + BPG < NT32) {
            const float4* pp = (const float4*)(x1 + (size_t)rcur * 64 + 16 * gq);
            const float4* pq = (const float4*)(xc + (size_t)ccur * 64 + 16 * gq);
            gp0 = pp[0]; gp1 = pp[1]; gp2 = pp[2]; gp3 = pp[3];
            gq0 = pq[0]; gq1 = pq[1]; gq2 = pq[2]; gq3 = pq[3];
        }

        // ---- C: e/srow visible (no vmcnt drain) ----
        asm volatile("s_waitcnt lgkmcnt(0)\n\ts_barrier" ::: "memory");

        // ---- D: layer 1 MFMA, relu, h write ----
        f32x4 acc1[4][2];
        #pragma unroll
        for (int m = 0; m < 4; ++m)
            #pragma unroll
            for (int n = 0; n < 2; ++n) {
                acc1[m][n][0] = b1v[m].x; acc1[m][n][1] = b1v[m].y;
                acc1[m][n][2] = b1v[m].z; acc1[m][n][3] = b1v[m].w;
            }
        __builtin_amdgcn_s_setprio(1);
        #pragma unroll
        for (int s = 0; s < 4; ++s) {
            bf16x8 eb[2];
            #pragma unroll
            for (int n = 0; n < 2; ++n) {
                int e = 16 * n + l15;
                int sidx = e * 128 + ((32 * s + 8 * lg) ^ ((e & 15) << 3));
                eb[n] = *(const bf16x8*)&e_lds[sidx];
            }
            #pragma unroll
            for (int m = 0; m < 4; ++m)
                #pragma unroll
                for (int n = 0; n < 2; ++n)
                    acc1[m][n] = __builtin_amdgcn_mfma_f32_16x16x32_bf16(
                        a1[m][s], eb[n], acc1[m][n], 0, 0, 0);
        }
        __builtin_amdgcn_s_setprio(0);
        #pragma unroll
        for (int m = 0; m < 4; ++m)
            #pragma unroll
            for (int n = 0; n < 2; ++n) {
                f32x4 vv = acc1[m][n];
                int e = 16 * n + l15;
                int hidc = w_h * 64 + 16 * m + 4 * lg;
                int sidx = e * 128 + (hidc ^ ((e & 15) << 3));
                uint2 w;
                w.x = pk2(fmaxf(vv[0], 0.f), fmaxf(vv[1], 0.f));
                w.y = pk2(fmaxf(vv[2], 0.f), fmaxf(vv[3], 0.f));
                *(uint2*)&h_lds[sidx] = w;
            }

        // ---- E: h visible ----
        asm volatile("s_waitcnt lgkmcnt(0)\n\ts_barrier" ::: "memory");

        // ---- F: layer 2 MFMA + scatter-max ----
        f32x4 acc2[2][2];
        #pragma unroll
        for (int m = 0; m < 2; ++m)
            #pragma unroll
            for (int n = 0; n < 2; ++n) {
                acc2[m][n][0] = b2v[n]; acc2[m][n][1] = b2v[n];
                acc2[m][n][2] = b2v[n]; acc2[m][n][3] = b2v[n];
            }
        __builtin_amdgcn_s_setprio(1);
        #pragma unroll
        for (int s = 0; s < 4; ++s) {
            bf16x8 ha[2];
            #pragma unroll
            for (int m = 0; m < 2; ++m) {
                int e = 16 * m + l15;
                int sidx = e * 128 + ((32 * s + 8 * lg) ^ ((e & 15) << 3));
                ha[m] = *(const bf16x8*)&h_lds[sidx];
            }
            #pragma unroll
            for (int m = 0; m < 2; ++m)
                #pragma unroll
                for (int n = 0; n < 2; ++n)
                    acc2[m][n] = __builtin_amdgcn_mfma_f32_16x16x32_bf16(
                        ha[m], b2f[s][n], acc2[m][n], 0, 0, 0);
        }
        __builtin_amdgcn_s_setprio(0);
        #pragma unroll
        for (int m = 0; m < 2; ++m) {
            int4 rows = *(const int4*)&srow[ib][16 * m + 4 * lg];
            #pragma unroll
            for (int n = 0; n < 2; ++n) {
                atomicMax(abase[n] + (size_t)rows.x * 128, enc(acc2[m][n][0]));
                atomicMax(abase[n] + (size_t)rows.y * 128, enc(acc2[m][n][1]));
                atomicMax(abase[n] + (size_t)rows.z * 128, enc(acc2[m][n][2]));
                atomicMax(abase[n] + (size_t)rows.w * 128, enc(acc2[m][n][3]));
            }
        }
    }
}

extern "C" void kernel_launch(void* const* d_in, const int* in_sizes, int n_in,
                              void* d_out, int out_size, void* d_ws, size_t ws_size,
                              hipStream_t stream) {
    const float* x1 = (const float*)d_in[0];
    const float* x2 = (const float*)d_in[1];
    const int*   ei1 = (const int*)d_in[2];
    const int*   ei2 = (const int*)d_in[3];
    const float* W1 = (const float*)d_in[4];
    const float* b1 = (const float*)d_in[5];
    const float* W2 = (const float*)d_in[6];
    const float* b2 = (const float*)d_in[7];
    unsigned* acc = (unsigned*)d_out;

    const int total = NN * 128;
    hipMemsetAsync(acc, 0, (size_t)total * sizeof(unsigned), stream);
    hipLaunchKernelGGL(edge_mlp, dim3(2 * BPG), dim3(128), 0, stream,
                       x1, x2, ei1, ei2, W1, b1, W2, b2, acc);
    hipLaunchKernelGGL(decode_acc, dim3((total + 255) / 256), dim3(256), 0, stream,
                       acc, total);
}